// Round 4
// baseline (229.861 us; speedup 1.0000x reference)
//
#include <hip/hip_runtime.h>
#include <hip/hip_bf16.h>

#define DM 1024
#define HID 64
#define NSTEP 6
#define RSTEP (1.0f/6.0f)

using short8  = __attribute__((ext_vector_type(8))) short;
using short4v = __attribute__((ext_vector_type(4))) short;
using f32x4   = __attribute__((ext_vector_type(4))) float;

// workspace byte offsets
#define WS_W1P 0          // 1024x64 bf16 packed A-frags (131072 B)
#define WS_W2P 131072     // 64x1024 bf16 packed A-frags (131072 B)
#define WS_GP  262144     // 64x64 bf16 packed A-frags (8192 B)
#define WS_U   270336     // 64 f32  (u = b2 @ W1k)

// LDS byte offsets (total 79360 B -> 2 blocks/CU on 160 KiB LDS)
#define L_ZH 0            // [32][1024] bf16 hi of z, XOR-swizzled (65536)
#define L_H0 65536        // H ping  [32][72] bf16, pitch 144 (4608)
#define L_H1 70144        // H pong
#define L_HB 74752        // Hb = (h/6)*Hsum
#define LDS_TOTAL 79360
#define HPITCH 144

// LDS-only barrier: order LDS ops, do NOT drain vmcnt (weight prefetches
// stay in flight; all cross-wave communication here is through LDS).
#define BAR() asm volatile("s_waitcnt lgkmcnt(0)\n\ts_barrier" ::: "memory")

__device__ __forceinline__ short f2bf(float f) {   // RNE via HW cvt
    __hip_bfloat16 h = __float2bfloat16(f);
    short s;
    __builtin_memcpy(&s, &h, 2);
    return s;
}
__device__ __forceinline__ float ftanh(float x) {
    x = fminf(fmaxf(x, -10.f), 10.f);
    float e = __expf(2.f * x);
    return __fdividef(e - 1.f, e + 1.f);
}

// ---------------- prep: pack weights to MFMA fragment layout ----------------
// A-frag layout for mfma_f32_16x16x32_bf16: lane l holds M-row (l&15),
// k = (l>>4)*8 + i (8 consecutive k). Packed so each lane loads one short8.
__global__ void k_prep(const float* __restrict__ W1, const float* __restrict__ W2,
                       const float* __restrict__ b2,
                       short* __restrict__ W1P, short* __restrict__ W2P,
                       short* __restrict__ GP, float* __restrict__ U) {
    __shared__ float red[4][64];
    int b = blockIdx.x;
    int t = threadIdx.x;           // 256 threads
    int l = t & 63, q4 = t >> 6;
    if (b < 128) {                 // W1k (1024x64) -> W1P[kk<32][c<4][l][8]
        if (t < 64) {
            int kk = b >> 2, c = b & 3;
            int col = c * 16 + (l & 15);
            int kb = kk * 32 + ((l >> 4) << 3);
            short8 v;
            #pragma unroll
            for (int i = 0; i < 8; ++i) v[i] = f2bf(W1[(kb + i) * HID + col]);
            *(short8*)(W1P + (((kk * 4 + c) * 64) + l) * 8) = v;
        }
    } else if (b < 256) {          // W2 (64x1024) -> W2P[kk2<2][ct<64][l][8]
        if (t < 64) {
            int bb = b - 128;
            int kk2 = bb >> 6, ct = bb & 63;
            int col = ct * 16 + (l & 15);
            int kb = kk2 * 32 + ((l >> 4) << 3);
            short8 v;
            #pragma unroll
            for (int i = 0; i < 8; ++i) v[i] = f2bf(W2[(kb + i) * DM + col]);
            *(short8*)(W2P + (((kk2 * 64 + ct) * 64) + l) * 8) = v;
        }
    } else if (b < 320) {          // G[j][i] = sum_d W2[j][d]*W1[d][i]; j = b-256
        int j = b - 256;
        float acc = 0.f;
        #pragma unroll 8
        for (int d = q4 * 256; d < q4 * 256 + 256; ++d)
            acc += W2[j * DM + d] * W1[d * HID + l];
        red[q4][l] = acc;
        __syncthreads();
        if (t < 64) {
            float a = red[0][l] + red[1][l] + red[2][l] + red[3][l];
            int kk = j >> 5, lk = (j >> 3) & 3, ii = j & 7, c = l >> 4, lo = l & 15;
            GP[(((kk * 4 + c) * 64) + lk * 16 + lo) * 8 + ii] = f2bf(a);
        }
    } else {                       // u[i] = sum_d b2[d]*W1[d][i]
        float acc = 0.f;
        #pragma unroll 8
        for (int d = q4 * 256; d < q4 * 256 + 256; ++d)
            acc += b2[d] * W1[d * HID + l];
        red[q4][l] = acc;
        __syncthreads();
        if (t < 64) U[l] = red[0][l] + red[1][l] + red[2][l] + red[3][l];
    }
}

// ---------------- fused RK4 neural-ODE kernel ----------------
// Block: 256 thr (4 waves), owns 32 rows of z (2 row-groups of 16).
// z master = f32 in REGISTERS: lane owns rows {l15, l15+16}, cols
// [w*256 + q*16 + hq*4 + j), q=0..15 -> f32x4 z[2][16] (static idx only!).
// zh (bf16 of z, LDS, swizzled) is the MFMA read image; P6 writes it, P1
// reads it; no LDS RMW, no residual bookkeeping.
// Weight frags are loaded ONCE per K-slice and reused for BOTH row-groups
// (halves per-CU L2 weight traffic vs 16-row blocks).
// MFMA: A = packed weights (M = out-col), B = z/H rows (N = row).
// D: m = (lane>>4)*4+reg (col), n = lane&15 (row).
// amdgpu_waves_per_eu(2,2): 2 blocks/CU is LDS-bound anyway; give the
// allocator the full 256-VGPR budget so z[2][16] never spills.
__global__ __launch_bounds__(256) __attribute__((amdgpu_waves_per_eu(2, 2)))
void k_ode(
        const float* __restrict__ X, const float* __restrict__ W1,
        const float* __restrict__ b1, const float* __restrict__ b2,
        const short* __restrict__ W1P, const short* __restrict__ W2P,
        const short* __restrict__ GP, const float* __restrict__ U,
        float* __restrict__ OUT) {
    extern __shared__ char smem[];
    const int t = threadIdx.x;
    const int lane = t & 63;
    const int w = t >> 6;                    // 0..3
    const int hq = lane >> 4;
    const int l15 = lane & 15;
    const int hcol0 = w * 16 + hq * 4;       // hid-col base (stage epilogues)
    const size_t row0 = (size_t)blockIdx.x * 32;

    int zb[2], swl[2];                       // row byte base + XOR swizzle
    #pragma unroll
    for (int g = 0; g < 2; ++g) {
        int r = g * 16 + l15;
        zb[g] = r << 11;
        swl[g] = ((r ^ (r >> 3)) & 7) << 4;
    }

    // per-lane persistent constants (L2-hot broadcasts)
    f32x4 u4   = *(const f32x4*)(U + hcol0);
    f32x4 b14  = *(const f32x4*)(b1 + hcol0);
    f32x4 w1t4 = *(const f32x4*)(W1 + DM * HID + hcol0);   // time row of W1
    short8 gf0 = *(const short8*)(GP + (w * 64 + lane) * 8);
    short8 gf1 = *(const short8*)(GP + ((4 + w) * 64 + lane) * 8);

    // ---- load owned x slice -> z regs (f32 master) + zh (bf16 LDS) ----
    f32x4 z[2][16];
    #pragma unroll
    for (int g = 0; g < 2; ++g) {
        const float* xrow = X + (row0 + g * 16 + l15) * DM;
        #pragma unroll
        for (int q = 0; q < 16; ++q) {
            int col = w * 256 + q * 16 + hq * 4;
            f32x4 v = *(const f32x4*)(xrow + col);
            z[g][q] = v;
            short4v hh;
            #pragma unroll
            for (int j = 0; j < 4; ++j) hh[j] = f2bf(v[j]);
            *(short4v*)(smem + L_ZH + ((zb[g] + col * 2) ^ swl[g])) = hh;
        }
    }
    BAR();

    for (int s = 0; s < NSTEP; ++s) {
        float tcur = RSTEP * (float)s;

        // P1: sz[g] = (z @ W1k) tile; K=1024 in 32 slices; weight frags
        // loaded once, used by both row-groups; 4 independent MFMA chains.
        f32x4 sz[2];
        {
            const short8* wp = (const short8*)W1P + (w * 64 + lane);
            f32x4 a0[2] = {(f32x4){0.f,0.f,0.f,0.f}, (f32x4){0.f,0.f,0.f,0.f}};
            f32x4 a1[2] = {(f32x4){0.f,0.f,0.f,0.f}, (f32x4){0.f,0.f,0.f,0.f}};
            #pragma unroll 4
            for (int kk = 0; kk < 32; kk += 2) {
                short8 wf0 = wp[kk * 256];
                short8 wf1 = wp[(kk + 1) * 256];
                #pragma unroll
                for (int g = 0; g < 2; ++g) {
                    short8 zf0 = *(const short8*)(smem + L_ZH + ((zb[g] + (kk << 6) + (hq << 4)) ^ swl[g]));
                    short8 zf1 = *(const short8*)(smem + L_ZH + ((zb[g] + ((kk + 1) << 6) + (hq << 4)) ^ swl[g]));
                    a0[g] = __builtin_amdgcn_mfma_f32_16x16x32_bf16(wf0, zf0, a0[g], 0, 0, 0);
                    a1[g] = __builtin_amdgcn_mfma_f32_16x16x32_bf16(wf1, zf1, a1[g], 0, 0, 0);
                }
            }
            sz[0] = a0[0] + a1[0];
            sz[1] = a0[1] + a1[1];
        }

        // P2: stage 1  H1 = tanh(sz + t*w1t + b1)
        f32x4 hsum[2];
        #pragma unroll
        for (int g = 0; g < 2; ++g) {
            short4v hc;
            #pragma unroll
            for (int j = 0; j < 4; ++j) {
                float T = sz[g][j] + tcur * w1t4[j] + b14[j];
                float h = ftanh(T);
                hsum[g][j] = h;
                hc[j] = f2bf(h);
            }
            *(short4v*)(smem + L_H0 + (g * 16 + l15) * HPITCH + hcol0 * 2) = hc;
        }
        BAR();

        // P3..P5: stages 2..4 via tiny H@G GEMM (G = W2@W1k)
        #pragma unroll
        for (int st = 0; st < 3; ++st) {
            const float c_i = (st == 2) ? RSTEP : (0.5f * RSTEP);
            const float t_i = tcur + ((st == 2) ? RSTEP : (0.5f * RSTEP));
            const float w_i = (st == 2) ? 1.f : 2.f;
            const int rbuf = (st & 1) ? L_H1 : L_H0;
            const int wbuf = (st & 1) ? L_H0 : L_H1;

            #pragma unroll
            for (int g = 0; g < 2; ++g) {
                short8 hf0 = *(const short8*)(smem + rbuf + (g * 16 + l15) * HPITCH + (hq << 4));
                short8 hf1 = *(const short8*)(smem + rbuf + (g * 16 + l15) * HPITCH + 64 + (hq << 4));
                f32x4 dd = (f32x4){0.f, 0.f, 0.f, 0.f};
                dd = __builtin_amdgcn_mfma_f32_16x16x32_bf16(gf0, hf0, dd, 0, 0, 0);
                dd = __builtin_amdgcn_mfma_f32_16x16x32_bf16(gf1, hf1, dd, 0, 0, 0);
                short4v hc;
                #pragma unroll
                for (int j = 0; j < 4; ++j) {
                    float T = sz[g][j] + c_i * (dd[j] + u4[j]) + t_i * w1t4[j] + b14[j];
                    float h = ftanh(T);
                    hsum[g][j] += w_i * h;
                    hc[j] = f2bf(h);
                }
                if (st < 2) {
                    *(short4v*)(smem + wbuf + (g * 16 + l15) * HPITCH + hcol0 * 2) = hc;
                } else {   // Hb = (h/6) * Hsum, GEMM2 B-operand
                    short4v hb4;
                    #pragma unroll
                    for (int j = 0; j < 4; ++j) hb4[j] = f2bf(hsum[g][j] * (RSTEP / 6.f));
                    *(short4v*)(smem + L_HB + (g * 16 + l15) * HPITCH + hcol0 * 2) = hb4;
                }
            }
            BAR();
        }

        // P6: z += Hb @ W2 + h*b2  (wave w owns cols [w*256, +256), both groups;
        // weight frags reused across row-groups)
        {
            short8 hb[2][2];
            #pragma unroll
            for (int g = 0; g < 2; ++g)
                #pragma unroll
                for (int kk2 = 0; kk2 < 2; ++kk2)
                    hb[g][kk2] = *(const short8*)(smem + L_HB +
                        (g * 16 + l15) * HPITCH + kk2 * 64 + (hq << 4));
            const short8* w2p8 = (const short8*)W2P;

            if (s < NSTEP - 1) {
                #pragma unroll
                for (int q = 0; q < 16; ++q) {
                    int ct = w * 16 + q;
                    short8 wa = w2p8[ct * 64 + lane];
                    short8 wb = w2p8[(64 + ct) * 64 + lane];
                    int col = w * 256 + q * 16 + hq * 4;
                    f32x4 b2v = *(const f32x4*)(b2 + col);
                    #pragma unroll
                    for (int g = 0; g < 2; ++g) {
                        f32x4 p = (f32x4){0.f, 0.f, 0.f, 0.f};
                        p = __builtin_amdgcn_mfma_f32_16x16x32_bf16(wa, hb[g][0], p, 0, 0, 0);
                        p = __builtin_amdgcn_mfma_f32_16x16x32_bf16(wb, hb[g][1], p, 0, 0, 0);
                        short4v nh;
                        #pragma unroll
                        for (int j = 0; j < 4; ++j) {
                            float v = z[g][q][j] + p[j] + RSTEP * b2v[j];
                            z[g][q][j] = v;
                            nh[j] = f2bf(v);
                        }
                        *(short4v*)(smem + L_ZH + ((zb[g] + col * 2) ^ swl[g])) = nh;
                    }
                }
            } else {   // last step: final z straight from regs to OUT (f32)
                #pragma unroll
                for (int q = 0; q < 16; ++q) {
                    int ct = w * 16 + q;
                    short8 wa = w2p8[ct * 64 + lane];
                    short8 wb = w2p8[(64 + ct) * 64 + lane];
                    int col = w * 256 + q * 16 + hq * 4;
                    f32x4 b2v = *(const f32x4*)(b2 + col);
                    #pragma unroll
                    for (int g = 0; g < 2; ++g) {
                        f32x4 p = (f32x4){0.f, 0.f, 0.f, 0.f};
                        p = __builtin_amdgcn_mfma_f32_16x16x32_bf16(wa, hb[g][0], p, 0, 0, 0);
                        p = __builtin_amdgcn_mfma_f32_16x16x32_bf16(wb, hb[g][1], p, 0, 0, 0);
                        f32x4 v;
                        #pragma unroll
                        for (int j = 0; j < 4; ++j)
                            v[j] = z[g][q][j] + p[j] + RSTEP * b2v[j];
                        *(f32x4*)(OUT + (row0 + g * 16 + l15) * DM + col) = v;
                    }
                }
            }
        }
        if (s < NSTEP - 1) BAR();
    }
}

extern "C" void kernel_launch(void* const* d_in, const int* in_sizes, int n_in,
                              void* d_out, int out_size, void* d_ws, size_t ws_size,
                              hipStream_t stream) {
    (void)in_sizes; (void)n_in; (void)out_size; (void)ws_size;
    const float* X  = (const float*)d_in[0];
    const float* W1 = (const float*)d_in[1];
    const float* b1 = (const float*)d_in[2];
    const float* W2 = (const float*)d_in[3];
    const float* b2 = (const float*)d_in[4];
    float* OUT = (float*)d_out;
    short* W1P = (short*)((char*)d_ws + WS_W1P);
    short* W2P = (short*)((char*)d_ws + WS_W2P);
    short* GP  = (short*)((char*)d_ws + WS_GP);
    float* U   = (float*)((char*)d_ws + WS_U);

    k_prep<<<321, 256, 0, stream>>>(W1, W2, b2, W1P, W2P, GP, U);
    k_ode<<<512, 256, LDS_TOTAL, stream>>>(X, W1, b1, b2, W1P, W2P, GP, U, OUT);
}